// Round 6
// baseline (1316.334 us; speedup 1.0000x reference)
//
#include <hip/hip_runtime.h>

#define NN   32768
#define NV   64
#define E0E  524288
#define HID  128
#define NL   4
#define NH   8
#define DH   16
#define SCALE 0.25f
#define PST  640   // P row stride: [q | k0 | v0 | k1 | v1]

__device__ __forceinline__ float gelu_f(float x) {
  return 0.5f * x * (1.0f + erff(x * 0.7071067811865475f));
}
__device__ __forceinline__ float sigmoid_f(float x) {
  return 1.0f / (1.0f + __expf(-x));
}

// ---------------- CSR build ----------------
__global__ void k_zero(int* c0, int* c1) {
  int i = blockIdx.x * 256 + threadIdx.x;
  if (i < NN) c0[i] = 0;
  if (i < NV) c1[i] = 0;
}
__global__ void k_hist(const int* __restrict__ dst, int nE, int* __restrict__ cnt) {
  int e = blockIdx.x * 256 + threadIdx.x;
  if (e < nE) atomicAdd(&cnt[dst[e]], 1);
}
template<int T, int CH>
__global__ void k_scan(int* __restrict__ cnt, int* __restrict__ rowptr, int total, int n) {
  __shared__ int sd[T];
  int t = threadIdx.x;
  int loc[CH];
  int base = t * CH;
  int s = 0;
  #pragma unroll
  for (int i = 0; i < CH; ++i) { loc[i] = cnt[base + i]; s += loc[i]; }
  sd[t] = s;
  __syncthreads();
  for (int off = 1; off < T; off <<= 1) {
    int v = (t >= off) ? sd[t - off] : 0;
    __syncthreads();
    sd[t] += v;
    __syncthreads();
  }
  int run = sd[t] - s;  // exclusive prefix
  #pragma unroll
  for (int i = 0; i < CH; ++i) { rowptr[base + i] = run; cnt[base + i] = run; run += loc[i]; }
  if (t == T - 1) rowptr[n] = total;
}
__global__ void k_scatter(const int* __restrict__ src, const int* __restrict__ dst,
                          int nE, int* __restrict__ cur, int* __restrict__ col) {
  int e = blockIdx.x * 256 + threadIdx.x;
  if (e < nE) {
    int pos = atomicAdd(&cur[dst[e]], 1);
    col[pos] = src[e];
  }
}
__global__ void k_copy4(const float4* __restrict__ a, float4* __restrict__ b, int n4) {
  int i = blockIdx.x * 256 + threadIdx.x;
  if (i < n4) b[i] = a[i];
}

// ---------------- fold a_rel/m_rel (and p_rel*SCALE) into W, TRANSPOSED [k][n] ----------------
__global__ void k_combine(const float* __restrict__ Wk, const float* __restrict__ Wv,
                          const float* __restrict__ bk, const float* __restrict__ bv,
                          const float* __restrict__ a_rel, const float* __restrict__ m_rel,
                          const float* __restrict__ p_rel,
                          float* __restrict__ CW, float* __restrict__ CB) {
  int blk = blockIdx.x;            // l*4 + mat
  int l = blk >> 2, mat = blk & 3;
  int rel = mat >> 1;
  int isK = ((mat & 1) == 0);
  const float* W  = (isK ? Wk : Wv) + (size_t)(l * 2) * HID * HID;   // source type is 'op'
  const float* bb = (isK ? bk : bv) + (l * 2) * HID;
  const float* R  = (isK ? a_rel : m_rel) + (size_t)((l * 2 + rel) * NH) * DH * DH;
  float* cw = CW + (size_t)blk * HID * HID;
  float* cb = CB + blk * HID;
  for (int o = threadIdx.x; o < HID * HID; o += blockDim.x) {
    int j = o >> 7, c = o & 127;
    int h = j >> 4, e = j & 15;
    float sc = isK ? (p_rel[(l * 2 + rel) * NH + h] * SCALE) : 1.0f;
    float s = 0.f;
    #pragma unroll
    for (int d = 0; d < DH; ++d)
      s += W[(size_t)(h * DH + d) * HID + c] * R[h * 256 + d * 16 + e];
    cw[(size_t)c * HID + j] = s * sc;   // transposed: [k][n]
  }
  if (threadIdx.x < HID) {
    int j = threadIdx.x, h = j >> 4, e = j & 15;
    float sc = isK ? (p_rel[(l * 2 + rel) * NH + h] * SCALE) : 1.0f;
    float s = 0.f;
    #pragma unroll
    for (int d = 0; d < DH; ++d) s += bb[h * DH + d] * R[h * 256 + d * 16 + e];
    cb[j] = s * sc;
  }
}

// transpose Wq[l,0] and Wa[l,0] (128x128 each) into [k][n] layout
__global__ void k_transp(const float* __restrict__ Wq, const float* __restrict__ Wa,
                         float* __restrict__ WqT, float* __restrict__ WaT) {
  int l = blockIdx.x;
  const float* src = (blockIdx.y == 0 ? Wq : Wa) + (size_t)(l * 2) * HID * HID;
  float*       dst = (blockIdx.y == 0 ? WqT : WaT) + (size_t)l * HID * HID;
  for (int o = threadIdx.x; o < HID * HID; o += 256) {
    int n = o >> 7, k = o & 127;
    dst[(size_t)k * HID + n] = src[o];
  }
}

// ---------------- f32 GEMM: out[m][cbase+c] = sum_k A[m][k]*WT[k][c] + bias[c] ----------------
// BM=64, BN=128, BK=32; 256 threads, 4x8 micro-tile. (r5: best so far)
struct WSet { const float* w[5]; const float* b[5]; };

__launch_bounds__(256)
__global__ void k_gemm(const float* __restrict__ A, int lda, WSet ws,
                       float* __restrict__ out, int ldo,
                       int gelu_in, const float* __restrict__ skipv) {
  __shared__ float As[64][36];    // [m][k], pad->36 (b128-aligned rows at k%4==0)
  __shared__ float Bs[32][132];   // [k][n], pad->132
  const float* __restrict__ WT   = ws.w[blockIdx.y];   // [k][n]
  const float* __restrict__ bias = ws.b[blockIdx.y];
  const int m0 = blockIdx.x * 64;
  const int t  = threadIdx.x;
  const int tx = t & 15, ty = t >> 4;
  const int sm = t >> 3;          // 0..31 A staging row
  const int sk = (t & 7) * 4;     // A staging k offset
  const int bk = t >> 5;          // 0..7  B staging k row
  const int bc = (t & 31) * 4;    // B staging col
  float acc[4][8] = {};
  for (int kt = 0; kt < HID; kt += 32) {
    #pragma unroll
    for (int p = 0; p < 2; ++p) {
      int m = sm + p * 32;
      float4 av = *(const float4*)(A + (size_t)(m0 + m) * lda + kt + sk);
      if (gelu_in) { av.x = gelu_f(av.x); av.y = gelu_f(av.y); av.z = gelu_f(av.z); av.w = gelu_f(av.w); }
      *(float4*)&As[m][sk] = av;
    }
    #pragma unroll
    for (int p = 0; p < 4; ++p) {
      int kk = bk + p * 8;
      *(float4*)&Bs[kk][bc] = *(const float4*)(WT + (size_t)(kt + kk) * HID + bc);
    }
    __syncthreads();
    #pragma unroll
    for (int k4 = 0; k4 < 32; k4 += 4) {
      float4 a4[4];
      #pragma unroll
      for (int r = 0; r < 4; ++r) a4[r] = *(const float4*)&As[4 * ty + r][k4];
      #pragma unroll
      for (int j = 0; j < 4; ++j) {
        float4 b0 = *(const float4*)&Bs[k4 + j][4 * tx];
        float4 b1 = *(const float4*)&Bs[k4 + j][64 + 4 * tx];
        #pragma unroll
        for (int i = 0; i < 4; ++i) {
          float ai = ((const float*)&a4[i])[j];
          acc[i][0] += ai * b0.x; acc[i][1] += ai * b0.y;
          acc[i][2] += ai * b0.z; acc[i][3] += ai * b0.w;
          acc[i][4] += ai * b1.x; acc[i][5] += ai * b1.y;
          acc[i][6] += ai * b1.z; acc[i][7] += ai * b1.w;
        }
      }
    }
    __syncthreads();
  }
  float g = 0.f, gm1 = 0.f;
  if (skipv) { g = sigmoid_f(*skipv); gm1 = 1.0f - g; }
  const int cbase = blockIdx.y * HID;
  #pragma unroll
  for (int i = 0; i < 4; ++i) {
    int m = m0 + 4 * ty + i;
    float* po = out + (size_t)m * ldo + cbase;
    #pragma unroll
    for (int hh = 0; hh < 2; ++hh) {
      int c = hh * 64 + 4 * tx;
      float4 bb = *(const float4*)(bias + c);
      float4 o;
      o.x = acc[i][hh * 4 + 0] + bb.x; o.y = acc[i][hh * 4 + 1] + bb.y;
      o.z = acc[i][hh * 4 + 2] + bb.z; o.w = acc[i][hh * 4 + 3] + bb.w;
      float* qp = po + c;
      if (skipv) {
        float4 xo = *(const float4*)qp;   // out aliases old-x (read-before-write, same elem)
        o.x = g * o.x + gm1 * xo.x; o.y = g * o.y + gm1 * xo.y;
        o.z = g * o.z + gm1 * xo.z; o.w = g * o.w + gm1 * xo.w;
      }
      *(float4*)qp = o;
    }
  }
}

// ---------------- relation 0: HEAD-SPLIT gather ----------------
// One wave per (dst, head); grid is head-major so all XCDs sweep the same
// 4.2 MB head-slice of P concurrently (fits one XCD L2; r5 showed 33.5 MB
// full-row working set -> only 54% L2 absorption). 16-lane groups process
// 4 edges in parallel, 2 chunks (8 edges) in flight per iteration.
__launch_bounds__(256)
__global__ void k_edge0(const float* __restrict__ P, const int* __restrict__ rowptr,
                        const int* __restrict__ col, float* __restrict__ agg) {
  int b = blockIdx.x;
  int h  = b >> 13;              // 8192 blocks per head
  int n  = (b & 8191) * 4 + (threadIdx.x >> 6);
  int lane = threadIdx.x & 63;
  int g = lane >> 4;             // edge slot 0..3
  int hoff = h * 16 + (lane & 15);
  float q = P[(size_t)n * PST + hoff];
  int e0 = rowptr[n], e1 = rowptr[n + 1];
  float acc = 0.f, wsum = 0.f;
  for (int e = e0; e < e1; e += 8) {
    int i0 = e + g, i1 = e + 4 + g;
    int c0 = col[min(i0, e1 - 1)];
    int c1 = col[min(i1, e1 - 1)];
    const float* r0 = P + (size_t)c0 * PST + hoff;
    const float* r1 = P + (size_t)c1 * PST + hoff;
    float k0 = r0[128], k1 = r1[128];
    float v0 = r0[256], v1 = r1[256];
    float p0 = q * k0, p1 = q * k1;
    p0 += __shfl_xor(p0, 1); p1 += __shfl_xor(p1, 1);
    p0 += __shfl_xor(p0, 2); p1 += __shfl_xor(p1, 2);
    p0 += __shfl_xor(p0, 4); p1 += __shfl_xor(p1, 4);
    p0 += __shfl_xor(p0, 8); p1 += __shfl_xor(p1, 8);
    float w0 = (i0 < e1) ? __expf(p0) : 0.f;
    float w1 = (i1 < e1) ? __expf(p1) : 0.f;
    acc += w0 * v0 + w1 * v1;
    wsum += w0 + w1;
  }
  acc += __shfl_xor(acc, 16); wsum += __shfl_xor(wsum, 16);
  acc += __shfl_xor(acc, 32); wsum += __shfl_xor(wsum, 32);
  if (lane < 16)
    agg[(size_t)n * HID + hoff] = acc / (wsum + 1e-16f);
}

// ---------------- relation 1: 8 chunk-blocks per virtual node, per-wave partials ----------------
__launch_bounds__(256)
__global__ void k_edge1(const float* __restrict__ P, const float* __restrict__ qv,
                        const int* __restrict__ rowptr, const int* __restrict__ col,
                        float* __restrict__ part) {
  int g = blockIdx.x >> 3, ch = blockIdx.x & 7;
  int w = threadIdx.x >> 6, lane = threadIdx.x & 63;
  int slot = ch * 4 + w;                     // 0..31
  float2 q = *(const float2*)(qv + g * HID + 2 * lane);
  int e0 = rowptr[g], e1 = rowptr[g + 1];
  int tot = e1 - e0;
  int len = (tot + 31) >> 5;
  int s0 = e0 + slot * len;
  int s1 = s0 + len; if (s1 > e1) s1 = e1;
  float acc0 = 0.f, acc1 = 0.f, wsum = 0.f;
  int e = s0;
  for (; e + 4 <= s1; e += 4) {
    const float* ra = P + (size_t)col[e]     * PST + 2 * lane;
    const float* rb = P + (size_t)col[e + 1] * PST + 2 * lane;
    const float* rc = P + (size_t)col[e + 2] * PST + 2 * lane;
    const float* rd = P + (size_t)col[e + 3] * PST + 2 * lane;
    float2 ka = *(const float2*)(ra + 384);
    float2 kb = *(const float2*)(rb + 384);
    float2 kc = *(const float2*)(rc + 384);
    float2 kd = *(const float2*)(rd + 384);
    float2 va = *(const float2*)(ra + 512);
    float2 vb = *(const float2*)(rb + 512);
    float2 vc = *(const float2*)(rc + 512);
    float2 vd = *(const float2*)(rd + 512);
    float pa = q.x * ka.x + q.y * ka.y;
    float pb = q.x * kb.x + q.y * kb.y;
    float pc = q.x * kc.x + q.y * kc.y;
    float pd = q.x * kd.x + q.y * kd.y;
    pa += __shfl_xor(pa, 1); pb += __shfl_xor(pb, 1); pc += __shfl_xor(pc, 1); pd += __shfl_xor(pd, 1);
    pa += __shfl_xor(pa, 2); pb += __shfl_xor(pb, 2); pc += __shfl_xor(pc, 2); pd += __shfl_xor(pd, 2);
    pa += __shfl_xor(pa, 4); pb += __shfl_xor(pb, 4); pc += __shfl_xor(pc, 4); pd += __shfl_xor(pd, 4);
    float wa = __expf(pa), wb = __expf(pb), wc = __expf(pc), wd = __expf(pd);
    wsum += (wa + wb) + (wc + wd);
    acc0 += wa * va.x + wb * vb.x + wc * vc.x + wd * vd.x;
    acc1 += wa * va.y + wb * vb.y + wc * vc.y + wd * vd.y;
  }
  for (; e < s1; ++e) {
    const float* row = P + (size_t)col[e] * PST + 2 * lane;
    float2 kv = *(const float2*)(row + 384);
    float p = q.x * kv.x + q.y * kv.y;
    p += __shfl_xor(p, 1); p += __shfl_xor(p, 2); p += __shfl_xor(p, 4);
    float ww = __expf(p);
    float2 vv = *(const float2*)(row + 512);
    wsum += ww; acc0 += ww * vv.x; acc1 += ww * vv.y;
  }
  float* pp = part + (size_t)(g * 32 + slot) * 192;
  pp[lane] = acc0; pp[64 + lane] = acc1; pp[128 + lane] = wsum;
}

__global__ void k_edge1red(const float* __restrict__ part, float* __restrict__ aggv) {
  int g = blockIdx.x, t = threadIdx.x;   // 64 threads
  float a0 = 0.f, a1 = 0.f, ws = 0.f;
  for (int s = 0; s < 32; ++s) {
    const float* p = part + (size_t)(g * 32 + s) * 192;
    a0 += p[t]; a1 += p[64 + t]; ws += p[128 + t];
  }
  float inv = 1.0f / (ws + 1e-16f);
  aggv[g * HID + 2 * t]     = a0 * inv;
  aggv[g * HID + 2 * t + 1] = a1 * inv;
}

// ---------------- small per-row projections on the 64 virtual nodes ----------------
__global__ void k_rowproj(const float* __restrict__ X, const float* __restrict__ W,
                          const float* __restrict__ bias, float* __restrict__ out) {
  __shared__ float xr[HID];
  int n = blockIdx.x, t = threadIdx.x;
  xr[t] = X[n * HID + t];
  __syncthreads();
  float s = bias[t];
  const float4* wr = (const float4*)(W + (size_t)t * HID);
  const float4* xx = (const float4*)xr;
  #pragma unroll 8
  for (int c = 0; c < HID / 4; ++c) {
    float4 w4 = wr[c], x4 = xx[c];
    s += x4.x * w4.x + x4.y * w4.y + x4.z * w4.z + x4.w * w4.w;
  }
  out[n * HID + t] = s;
}

__global__ void k_ov(const float* __restrict__ aggv, const float* __restrict__ Wa,
                     const float* __restrict__ ba, const float* __restrict__ skipv,
                     float* __restrict__ xv, float* __restrict__ outs) {
  __shared__ float xr[HID];
  int g = blockIdx.x, t = threadIdx.x;
  xr[t] = gelu_f(aggv[g * HID + t]);
  __syncthreads();
  float s = ba[t];
  const float4* wr = (const float4*)(Wa + (size_t)t * HID);
  const float4* xx = (const float4*)xr;
  #pragma unroll 8
  for (int c = 0; c < HID / 4; ++c) {
    float4 w4 = wr[c], x4 = xx[c];
    s += x4.x * w4.x + x4.y * w4.y + x4.z * w4.z + x4.w * w4.w;
  }
  float gg = sigmoid_f(*skipv);
  float nv2 = gg * s + (1.f - gg) * xv[g * HID + t];
  xv[g * HID + t] = nv2;
  outs[g * HID + t] = nv2;
}

// ---------------- JK attention + node/graph MLPs: one block per virtual node ----------------
struct TailW {
  const float *win, *bin, *wout, *bout;
  const float *nw0, *nb0, *nw1, *nb1, *nw2, *nb2, *nw3, *nb3, *nw4, *nb4, *nw5, *nb5, *nw6, *nb6;
  const float *gw0, *gb0, *gw1, *gb1;
};

__launch_bounds__(128)
__global__ void k_final(const float* __restrict__ outsv, TailW tw, float* __restrict__ outp) {
  __shared__ float xs[4][HID], qq[4][HID], kk[4][HID], vv[4][HID], oo[4][HID];
  __shared__ float att[NH][4][4];
  __shared__ float hb[HID], tb[64];
  int b = blockIdx.x, t = threadIdx.x;
  for (int l = 0; l < 4; ++l) xs[l][t] = outsv[(size_t)(l * NV + b) * HID + t];
  __syncthreads();
  for (int l = 0; l < 4; ++l) {
    float sq = tw.bin[t], sk = tw.bin[t + 128], sv = tw.bin[t + 256];
    const float* wq = tw.win + (size_t)t * HID;
    const float* wk = tw.win + (size_t)(t + 128) * HID;
    const float* wv = tw.win + (size_t)(t + 256) * HID;
    for (int c = 0; c < HID; ++c) {
      float x = xs[l][c];
      sq += x * wq[c]; sk += x * wk[c]; sv += x * wv[c];
    }
    qq[l][t] = sq; kk[l][t] = sk; vv[l][t] = sv;
  }
  __syncthreads();
  {
    int h = t >> 4, ql = (t >> 2) & 3, kl = t & 3;
    float s = 0.f;
    #pragma unroll
    for (int d = 0; d < DH; ++d) s += qq[ql][h * DH + d] * kk[kl][h * DH + d];
    att[h][ql][kl] = s * SCALE;
  }
  __syncthreads();
  if (t < 32) {
    int h = t >> 2, ql = t & 3;
    float m = att[h][ql][0];
    for (int k2 = 1; k2 < 4; ++k2) m = fmaxf(m, att[h][ql][k2]);
    float e[4], s = 0.f;
    for (int k2 = 0; k2 < 4; ++k2) { e[k2] = __expf(att[h][ql][k2] - m); s += e[k2]; }
    for (int k2 = 0; k2 < 4; ++k2) att[h][ql][k2] = e[k2] / s;
  }
  __syncthreads();
  {
    int h = t >> 4;
    #pragma unroll
    for (int ql = 0; ql < 4; ++ql) {
      float s = 0.f;
      #pragma unroll
      for (int kl = 0; kl < 4; ++kl) s += att[h][ql][kl] * vv[kl][t];
      oo[ql][t] = s;
    }
  }
  __syncthreads();
  {
    float s = 0.f;
    const float* wr = tw.wout + (size_t)t * HID;
    for (int l = 0; l < 4; ++l) {
      float ss = tw.bout[t];
      for (int c = 0; c < HID; ++c) ss += oo[l][c] * wr[c];
      s += ss;
    }
    hb[t] = s;
  }
  __syncthreads();
  if (t < 64) { float s = tw.nb0[t]; const float* wr = tw.nw0 + t * 128; for (int c = 0; c < 128; ++c) s += hb[c] * wr[c]; tb[t] = gelu_f(s); }
  __syncthreads();
  if (t < 32) { float s = tw.nb1[t]; const float* wr = tw.nw1 + t * 64;  for (int c = 0; c < 64;  ++c) s += tb[c] * wr[c]; hb[t] = gelu_f(s); }
  __syncthreads();
  if (t < 16) { float s = tw.nb2[t]; const float* wr = tw.nw2 + t * 32;  for (int c = 0; c < 32;  ++c) s += hb[c] * wr[c]; tb[t] = gelu_f(s); }
  __syncthreads();
  if (t < 8)  { float s = tw.nb3[t]; const float* wr = tw.nw3 + t * 16;  for (int c = 0; c < 16;  ++c) s += tb[c] * wr[c]; hb[t] = gelu_f(s); }
  __syncthreads();
  if (t < 4)  { float s = tw.nb4[t]; const float* wr = tw.nw4 + t * 8;   for (int c = 0; c < 8;   ++c) s += hb[c] * wr[c]; tb[t] = gelu_f(s); }
  __syncthreads();
  if (t < 2)  { float s = tw.nb5[t]; const float* wr = tw.nw5 + t * 4;   for (int c = 0; c < 4;   ++c) s += tb[c] * wr[c]; hb[t] = gelu_f(s); }
  __syncthreads();
  if (t == 0) {
    float s = hb[0] * tw.nw6[0] + hb[1] * tw.nw6[1] + tw.nb6[0];
    float g0 = gelu_f(s * tw.gw0[0] + tw.gb0[0]);
    float g1 = gelu_f(s * tw.gw0[1] + tw.gb0[1]);
    outp[b] = g0 * tw.gw1[0] + g1 * tw.gw1[1] + tw.gb1[0];
  }
}

// ---------------- host ----------------
extern "C" void kernel_launch(void* const* d_in, const int* in_sizes, int n_in,
                              void* d_out, int out_size, void* d_ws, size_t ws_size,
                              hipStream_t stream) {
  const float* x_op = (const float*)d_in[0];
  const float* x_v  = (const float*)d_in[1];
  const int*   ei0  = (const int*)d_in[2];
  const int*   ei1  = (const int*)d_in[3];
  const float* Wk   = (const float*)d_in[4];
  const float* Wq   = (const float*)d_in[5];
  const float* Wv   = (const float*)d_in[6];
  const float* Wa   = (const float*)d_in[7];
  const float* bk   = (const float*)d_in[8];
  const float* bq   = (const float*)d_in[9];
  const float* bv   = (const float*)d_in[10];
  const float* ba   = (const float*)d_in[11];
  const float* skip = (const float*)d_in[12];
  const float* a_rel = (const float*)d_in[13];
  const float* m_rel = (const float*)d_in[14];
  const float* p_rel = (const float*)d_in[15];
  (void)in_sizes; (void)n_in; (void)out_size; (void)ws_size;

  char* wsp = (char*)d_ws;
  size_t off = 0;
  auto alloc = [&](size_t bytes) -> void* {
    void* p = wsp + off;
    off += (bytes + 255) & ~(size_t)255;
    return p;
  };
  float* P     = (float*)alloc((size_t)NN * PST * 4);      // 83.9 MB
  float* xop   = (float*)alloc((size_t)NN * HID * 4);      // 16.8 MB
  float* agg   = (float*)alloc((size_t)NN * HID * 4);      // 16.8 MB
  float* CW    = (float*)alloc((size_t)16 * HID * HID * 4);
  float* CB    = (float*)alloc((size_t)16 * HID * 4);
  float* WqT   = (float*)alloc((size_t)NL * HID * HID * 4);
  float* WaT   = (float*)alloc((size_t)NL * HID * HID * 4);
  float* xv    = (float*)alloc((size_t)NV * HID * 4);
  float* qv    = (float*)alloc((size_t)NV * HID * 4);
  float* aggv  = (float*)alloc((size_t)NV * HID * 4);
  float* outsv = (float*)alloc((size_t)NL * NV * HID * 4);
  float* part  = (float*)alloc((size_t)NV * 32 * 192 * 4); // 1.57 MB edge1 partials
  int* rowptr0 = (int*)alloc((size_t)(NN + 1) * 4);
  int* cur0    = (int*)alloc((size_t)NN * 4);
  int* col0    = (int*)alloc((size_t)E0E * 4);
  int* rowptr1 = (int*)alloc((size_t)(NV + 1) * 4);
  int* cur1    = (int*)alloc((size_t)NV * 4);
  int* col1    = (int*)alloc((size_t)NN * 4);

  // CSR build (ws is re-poisoned each call, so rebuild every time)
  k_zero<<<NN / 256, 256, 0, stream>>>(cur0, cur1);
  k_hist<<<E0E / 256, 256, 0, stream>>>(ei0 + E0E, E0E, cur0);
  k_hist<<<NN / 256, 256, 0, stream>>>(ei1 + NN, NN, cur1);
  k_scan<1024, 32><<<1, 1024, 0, stream>>>(cur0, rowptr0, E0E, NN);
  k_scan<64, 1><<<1, 64, 0, stream>>>(cur1, rowptr1, NN, NV);
  k_scatter<<<E0E / 256, 256, 0, stream>>>(ei0, ei0 + E0E, E0E, cur0, col0);
  k_scatter<<<NN / 256, 256, 0, stream>>>(ei1, ei1 + NN, NN, cur1, col1);
  k_copy4<<<(NN * HID / 4 + 255) / 256, 256, 0, stream>>>((const float4*)x_op, (float4*)xop, NN * HID / 4);
  k_copy4<<<(NV * HID / 4 + 255) / 256, 256, 0, stream>>>((const float4*)x_v, (float4*)xv, NV * HID / 4);
  k_combine<<<16, 256, 0, stream>>>(Wk, Wv, bk, bv, a_rel, m_rel, p_rel, CW, CB);
  k_transp<<<dim3(4, 2), 256, 0, stream>>>(Wq, Wa, WqT, WaT);

  for (int l = 0; l < NL; ++l) {
    WSet wp;
    wp.w[0] = WqT + (size_t)l * HID * HID;  wp.b[0] = bq + (l * 2 + 0) * HID;
    for (int m = 0; m < 4; ++m) {
      wp.w[1 + m] = CW + (size_t)(l * 4 + m) * HID * HID;
      wp.b[1 + m] = CB + (l * 4 + m) * HID;
    }
    // P = xop @ [Wq | Wk*a0 | Wv*m0 | Wk*a1 | Wv*m1]^T   (p_rel*SCALE folded into K mats)
    k_gemm<<<dim3(NN / 64, 5), 256, 0, stream>>>(xop, HID, wp, P, PST, 0, nullptr);
    k_rowproj<<<NV, HID, 0, stream>>>(xv, Wq + (size_t)(l * 2 + 1) * HID * HID,
                                      bq + (l * 2 + 1) * HID, qv);
    k_edge0<<<NN / 4 * NH, 256, 0, stream>>>(P, rowptr0, col0, agg);
    k_edge1<<<NV * 8, 256, 0, stream>>>(P, qv, rowptr1, col1, part);
    k_edge1red<<<NV, 64, 0, stream>>>(part, aggv);
    WSet wo;
    wo.w[0] = WaT + (size_t)l * HID * HID; wo.b[0] = ba + (l * 2 + 0) * HID;
    for (int m = 1; m < 5; ++m) { wo.w[m] = wo.w[0]; wo.b[m] = wo.b[0]; }
    // xop = g*(gelu(agg) @ Wa^T + ba) + (1-g)*xop
    k_gemm<<<dim3(NN / 64, 1), 256, 0, stream>>>(agg, HID, wo, xop, HID, 1, skip + l * 2 + 0);
    k_ov<<<NV, HID, 0, stream>>>(aggv, Wa + (size_t)(l * 2 + 1) * HID * HID,
                                 ba + (l * 2 + 1) * HID, skip + l * 2 + 1,
                                 xv, outsv + (size_t)l * NV * HID);
  }

  TailW tw;
  tw.win  = (const float*)d_in[16]; tw.bin  = (const float*)d_in[17];
  tw.wout = (const float*)d_in[18]; tw.bout = (const float*)d_in[19];
  tw.nw0 = (const float*)d_in[20]; tw.nb0 = (const float*)d_in[21];
  tw.nw1 = (const float*)d_in[22]; tw.nb1 = (const float*)d_in[23];
  tw.nw2 = (const float*)d_in[24]; tw.nb2 = (const float*)d_in[25];
  tw.nw3 = (const float*)d_in[26]; tw.nb3 = (const float*)d_in[27];
  tw.nw4 = (const float*)d_in[28]; tw.nb4 = (const float*)d_in[29];
  tw.nw5 = (const float*)d_in[30]; tw.nb5 = (const float*)d_in[31];
  tw.nw6 = (const float*)d_in[32]; tw.nb6 = (const float*)d_in[33];
  tw.gw0 = (const float*)d_in[34]; tw.gb0 = (const float*)d_in[35];
  tw.gw1 = (const float*)d_in[36]; tw.gb1 = (const float*)d_in[37];
  k_final<<<NV, HID, 0, stream>>>(outsv, tw, (float*)d_out);
}

// Round 7
// 1259.948 us; speedup vs baseline: 1.0448x; 1.0448x over previous
//
#include <hip/hip_runtime.h>

#define NN   32768
#define NV   64
#define E0E  524288
#define HID  128
#define NL   4
#define NH   8
#define DH   16
#define SCALE 0.25f
#define PST  640   // P row: [q(128) | kv0 interleaved (256) | kv1 interleaved (256)]
                   // kv region: head h -> k at h*32+0..15, v at h*32+16..31

__device__ __forceinline__ float gelu_f(float x) {
  return 0.5f * x * (1.0f + erff(x * 0.7071067811865475f));
}
__device__ __forceinline__ float sigmoid_f(float x) {
  return 1.0f / (1.0f + __expf(-x));
}

// ---------------- CSR build ----------------
__global__ void k_zero(int* c0, int* c1) {
  int i = blockIdx.x * 256 + threadIdx.x;
  if (i < NN) c0[i] = 0;
  if (i < NV) c1[i] = 0;
}
__global__ void k_hist(const int* __restrict__ dst, int nE, int* __restrict__ cnt) {
  int e = blockIdx.x * 256 + threadIdx.x;
  if (e < nE) atomicAdd(&cnt[dst[e]], 1);
}
template<int T, int CH>
__global__ void k_scan(int* __restrict__ cnt, int* __restrict__ rowptr, int total, int n) {
  __shared__ int sd[T];
  int t = threadIdx.x;
  int loc[CH];
  int base = t * CH;
  int s = 0;
  #pragma unroll
  for (int i = 0; i < CH; ++i) { loc[i] = cnt[base + i]; s += loc[i]; }
  sd[t] = s;
  __syncthreads();
  for (int off = 1; off < T; off <<= 1) {
    int v = (t >= off) ? sd[t - off] : 0;
    __syncthreads();
    sd[t] += v;
    __syncthreads();
  }
  int run = sd[t] - s;  // exclusive prefix
  #pragma unroll
  for (int i = 0; i < CH; ++i) { rowptr[base + i] = run; cnt[base + i] = run; run += loc[i]; }
  if (t == T - 1) rowptr[n] = total;
}
__global__ void k_scatter(const int* __restrict__ src, const int* __restrict__ dst,
                          int nE, int* __restrict__ cur, int* __restrict__ col) {
  int e = blockIdx.x * 256 + threadIdx.x;
  if (e < nE) {
    int pos = atomicAdd(&cur[dst[e]], 1);
    col[pos] = src[e];
  }
}
__global__ void k_copy4(const float4* __restrict__ a, float4* __restrict__ b, int n4) {
  int i = blockIdx.x * 256 + threadIdx.x;
  if (i < n4) b[i] = a[i];
}

// ---------------- fold a_rel/m_rel (+p_rel*SCALE) into W, [k][n], kv-INTERLEAVED cols ----------
// Block blk = l*4 + mat; mat: rel = mat>>1, half = mat&1 (heads half*4..half*4+3).
// Chunk col j: pair=j>>5 -> h=half*4+pair; inner=j&31: inner<16 => k-col (Wk,a_rel,p*SCALE),
// else v-col (Wv,m_rel). e = inner&15.
__global__ void k_combine(const float* __restrict__ Wk, const float* __restrict__ Wv,
                          const float* __restrict__ bk, const float* __restrict__ bv,
                          const float* __restrict__ a_rel, const float* __restrict__ m_rel,
                          const float* __restrict__ p_rel,
                          float* __restrict__ CW, float* __restrict__ CB) {
  int blk = blockIdx.x;
  int l = blk >> 2, mat = blk & 3;
  int rel = mat >> 1, half = mat & 1;
  const float* Ra = a_rel + (size_t)((l * 2 + rel) * NH) * DH * DH;
  const float* Rm = m_rel + (size_t)((l * 2 + rel) * NH) * DH * DH;
  float* cw = CW + (size_t)blk * HID * HID;
  float* cb = CB + blk * HID;
  for (int o = threadIdx.x; o < HID * HID; o += blockDim.x) {
    int j = o >> 7, c = o & 127;
    int pair = j >> 5, inner = j & 31;
    int h = half * 4 + pair;
    int isK = inner < 16;
    int e = inner & 15;
    const float* W = (isK ? Wk : Wv) + (size_t)(l * 2) * HID * HID;
    const float* R = isK ? Ra : Rm;
    float sc = isK ? (p_rel[(l * 2 + rel) * NH + h] * SCALE) : 1.0f;
    float s = 0.f;
    #pragma unroll
    for (int d = 0; d < DH; ++d)
      s += W[(size_t)(h * DH + d) * HID + c] * R[h * 256 + d * 16 + e];
    cw[(size_t)c * HID + j] = s * sc;   // [k][n]
  }
  if (threadIdx.x < HID) {
    int j = threadIdx.x;
    int pair = j >> 5, inner = j & 31;
    int h = half * 4 + pair;
    int isK = inner < 16;
    int e = inner & 15;
    const float* bb = (isK ? bk : bv) + (l * 2) * HID;
    const float* R = isK ? Ra : Rm;
    float sc = isK ? (p_rel[(l * 2 + rel) * NH + h] * SCALE) : 1.0f;
    float s = 0.f;
    #pragma unroll
    for (int d = 0; d < DH; ++d) s += bb[h * DH + d] * R[h * 256 + d * 16 + e];
    cb[j] = s * sc;
  }
}

// transpose Wq[l,0] and Wa[l,0] (128x128 each) into [k][n] layout
__global__ void k_transp(const float* __restrict__ Wq, const float* __restrict__ Wa,
                         float* __restrict__ WqT, float* __restrict__ WaT) {
  int l = blockIdx.x;
  const float* src = (blockIdx.y == 0 ? Wq : Wa) + (size_t)(l * 2) * HID * HID;
  float*       dst = (blockIdx.y == 0 ? WqT : WaT) + (size_t)l * HID * HID;
  for (int o = threadIdx.x; o < HID * HID; o += 256) {
    int n = o >> 7, k = o & 127;
    dst[(size_t)k * HID + n] = src[o];
  }
}

// ---------------- f32 GEMM: out[m][cbase+c] = sum_k A[m][k]*WT[k][c] + bias[c] ----------------
// BM=64, BN=128, BK=32; 256 threads, 4x8 micro-tile. (r5 config: best so far)
struct WSet { const float* w[5]; const float* b[5]; };

__launch_bounds__(256)
__global__ void k_gemm(const float* __restrict__ A, int lda, WSet ws,
                       float* __restrict__ out, int ldo,
                       int gelu_in, const float* __restrict__ skipv) {
  __shared__ float As[64][36];    // [m][k], pad->36 (b128-aligned rows at k%4==0)
  __shared__ float Bs[32][132];   // [k][n], pad->132
  const float* __restrict__ WT   = ws.w[blockIdx.y];   // [k][n]
  const float* __restrict__ bias = ws.b[blockIdx.y];
  const int m0 = blockIdx.x * 64;
  const int t  = threadIdx.x;
  const int tx = t & 15, ty = t >> 4;
  const int sm = t >> 3;          // 0..31 A staging row
  const int sk = (t & 7) * 4;     // A staging k offset
  const int bk = t >> 5;          // 0..7  B staging k row
  const int bc = (t & 31) * 4;    // B staging col
  float acc[4][8] = {};
  for (int kt = 0; kt < HID; kt += 32) {
    #pragma unroll
    for (int p = 0; p < 2; ++p) {
      int m = sm + p * 32;
      float4 av = *(const float4*)(A + (size_t)(m0 + m) * lda + kt + sk);
      if (gelu_in) { av.x = gelu_f(av.x); av.y = gelu_f(av.y); av.z = gelu_f(av.z); av.w = gelu_f(av.w); }
      *(float4*)&As[m][sk] = av;
    }
    #pragma unroll
    for (int p = 0; p < 4; ++p) {
      int kk = bk + p * 8;
      *(float4*)&Bs[kk][bc] = *(const float4*)(WT + (size_t)(kt + kk) * HID + bc);
    }
    __syncthreads();
    #pragma unroll
    for (int k4 = 0; k4 < 32; k4 += 4) {
      float4 a4[4];
      #pragma unroll
      for (int r = 0; r < 4; ++r) a4[r] = *(const float4*)&As[4 * ty + r][k4];
      #pragma unroll
      for (int j = 0; j < 4; ++j) {
        float4 b0 = *(const float4*)&Bs[k4 + j][4 * tx];
        float4 b1 = *(const float4*)&Bs[k4 + j][64 + 4 * tx];
        #pragma unroll
        for (int i = 0; i < 4; ++i) {
          float ai = ((const float*)&a4[i])[j];
          acc[i][0] += ai * b0.x; acc[i][1] += ai * b0.y;
          acc[i][2] += ai * b0.z; acc[i][3] += ai * b0.w;
          acc[i][4] += ai * b1.x; acc[i][5] += ai * b1.y;
          acc[i][6] += ai * b1.z; acc[i][7] += ai * b1.w;
        }
      }
    }
    __syncthreads();
  }
  float g = 0.f, gm1 = 0.f;
  if (skipv) { g = sigmoid_f(*skipv); gm1 = 1.0f - g; }
  const int cbase = blockIdx.y * HID;
  #pragma unroll
  for (int i = 0; i < 4; ++i) {
    int m = m0 + 4 * ty + i;
    float* po = out + (size_t)m * ldo + cbase;
    #pragma unroll
    for (int hh = 0; hh < 2; ++hh) {
      int c = hh * 64 + 4 * tx;
      float4 bb = *(const float4*)(bias + c);
      float4 o;
      o.x = acc[i][hh * 4 + 0] + bb.x; o.y = acc[i][hh * 4 + 1] + bb.y;
      o.z = acc[i][hh * 4 + 2] + bb.z; o.w = acc[i][hh * 4 + 3] + bb.w;
      float* qp = po + c;
      if (skipv) {
        float4 xo = *(const float4*)qp;   // out aliases old-x (read-before-write, same elem)
        o.x = g * o.x + gm1 * xo.x; o.y = g * o.y + gm1 * xo.y;
        o.z = g * o.z + gm1 * xo.z; o.w = g * o.w + gm1 * xo.w;
      }
      *(float4*)qp = o;
    }
  }
}

// ---------------- relation 0: head-split gather, ONE 128-B line per (edge,head) --------------
// r6 lesson: head-split with k/v 512B apart fetched 2 half-used lines per edge (FETCH 341MB).
// With kv interleaved, each (edge,head) reads k[16]+v[16] = one fully-used 128B line.
// One wave per (dst,head), grid head-major (per-head slice 4.2MB ~ XCD L2).
__launch_bounds__(256)
__global__ void k_edge0(const float* __restrict__ P, const int* __restrict__ rowptr,
                        const int* __restrict__ col, float* __restrict__ agg) {
  int b = blockIdx.x;
  int h  = b >> 13;              // 8192 blocks per head
  int n  = (b & 8191) * 4 + (threadIdx.x >> 6);
  int lane = threadIdx.x & 63;
  int g = lane >> 4;             // edge slot 0..3
  int c16 = lane & 15;
  float q = P[(size_t)n * PST + h * 16 + c16];
  const float* Pkv = P + 128 + h * 32 + c16;
  int e0 = rowptr[n], e1 = rowptr[n + 1];
  float acc = 0.f, wsum = 0.f;
  for (int e = e0; e < e1; e += 8) {
    int i0 = e + g, i1 = e + 4 + g;
    int c0 = col[min(i0, e1 - 1)];
    int c1 = col[min(i1, e1 - 1)];
    const float* r0 = Pkv + (size_t)c0 * PST;
    const float* r1 = Pkv + (size_t)c1 * PST;
    float k0 = r0[0], k1 = r1[0];
    float v0 = r0[16], v1 = r1[16];
    float p0 = q * k0, p1 = q * k1;
    p0 += __shfl_xor(p0, 1); p1 += __shfl_xor(p1, 1);
    p0 += __shfl_xor(p0, 2); p1 += __shfl_xor(p1, 2);
    p0 += __shfl_xor(p0, 4); p1 += __shfl_xor(p1, 4);
    p0 += __shfl_xor(p0, 8); p1 += __shfl_xor(p1, 8);
    float w0 = (i0 < e1) ? __expf(p0) : 0.f;
    float w1 = (i1 < e1) ? __expf(p1) : 0.f;
    acc += w0 * v0 + w1 * v1;
    wsum += w0 + w1;
  }
  acc += __shfl_xor(acc, 16); wsum += __shfl_xor(wsum, 16);
  acc += __shfl_xor(acc, 32); wsum += __shfl_xor(wsum, 32);
  if (lane < 16)
    agg[(size_t)n * HID + h * 16 + c16] = acc / (wsum + 1e-16f);
}

// ---------------- relation 1: 8 chunk-blocks per virtual node, kv1-interleaved ---------------
// 8-lane group per head: lane = h*8+j; k at 384+h*32+2j (float2), v at +16.
__launch_bounds__(256)
__global__ void k_edge1(const float* __restrict__ P, const float* __restrict__ qv,
                        const int* __restrict__ rowptr, const int* __restrict__ col,
                        float* __restrict__ part) {
  int g = blockIdx.x >> 3, ch = blockIdx.x & 7;
  int w = threadIdx.x >> 6, lane = threadIdx.x & 63;
  int slot = ch * 4 + w;                     // 0..31
  int hh = lane >> 3, j2 = (lane & 7) * 2;
  float2 q = *(const float2*)(qv + g * HID + hh * 16 + j2);
  const float* Pk = P + 384 + hh * 32 + j2;
  int e0 = rowptr[g], e1 = rowptr[g + 1];
  int tot = e1 - e0;
  int len = (tot + 31) >> 5;
  int s0 = e0 + slot * len;
  int s1 = s0 + len; if (s1 > e1) s1 = e1;
  float acc0 = 0.f, acc1 = 0.f, wsum = 0.f;
  int e = s0;
  for (; e + 4 <= s1; e += 4) {
    const float* ra = Pk + (size_t)col[e]     * PST;
    const float* rb = Pk + (size_t)col[e + 1] * PST;
    const float* rc = Pk + (size_t)col[e + 2] * PST;
    const float* rd = Pk + (size_t)col[e + 3] * PST;
    float2 ka = *(const float2*)ra;
    float2 kb = *(const float2*)rb;
    float2 kc = *(const float2*)rc;
    float2 kd = *(const float2*)rd;
    float2 va = *(const float2*)(ra + 16);
    float2 vb = *(const float2*)(rb + 16);
    float2 vc = *(const float2*)(rc + 16);
    float2 vd = *(const float2*)(rd + 16);
    float pa = q.x * ka.x + q.y * ka.y;
    float pb = q.x * kb.x + q.y * kb.y;
    float pc = q.x * kc.x + q.y * kc.y;
    float pd = q.x * kd.x + q.y * kd.y;
    pa += __shfl_xor(pa, 1); pb += __shfl_xor(pb, 1); pc += __shfl_xor(pc, 1); pd += __shfl_xor(pd, 1);
    pa += __shfl_xor(pa, 2); pb += __shfl_xor(pb, 2); pc += __shfl_xor(pc, 2); pd += __shfl_xor(pd, 2);
    pa += __shfl_xor(pa, 4); pb += __shfl_xor(pb, 4); pc += __shfl_xor(pc, 4); pd += __shfl_xor(pd, 4);
    float wa = __expf(pa), wb = __expf(pb), wc = __expf(pc), wd = __expf(pd);
    wsum += (wa + wb) + (wc + wd);
    acc0 += wa * va.x + wb * vb.x + wc * vc.x + wd * vd.x;
    acc1 += wa * va.y + wb * vb.y + wc * vc.y + wd * vd.y;
  }
  for (; e < s1; ++e) {
    const float* row = Pk + (size_t)col[e] * PST;
    float2 kv = *(const float2*)row;
    float p = q.x * kv.x + q.y * kv.y;
    p += __shfl_xor(p, 1); p += __shfl_xor(p, 2); p += __shfl_xor(p, 4);
    float ww = __expf(p);
    float2 vv = *(const float2*)(row + 16);
    wsum += ww; acc0 += ww * vv.x; acc1 += ww * vv.y;
  }
  float* pp = part + (size_t)(g * 32 + slot) * 192;
  pp[lane] = acc0; pp[64 + lane] = acc1; pp[128 + lane] = wsum;
}

__global__ void k_edge1red(const float* __restrict__ part, float* __restrict__ aggv) {
  int g = blockIdx.x, t = threadIdx.x;   // 64 threads; lane t held channels (t>>3)*16+2*(t&7)
  float a0 = 0.f, a1 = 0.f, ws = 0.f;
  for (int s = 0; s < 32; ++s) {
    const float* p = part + (size_t)(g * 32 + s) * 192;
    a0 += p[t]; a1 += p[64 + t]; ws += p[128 + t];
  }
  float inv = 1.0f / (ws + 1e-16f);
  int cc = (t >> 3) * 16 + 2 * (t & 7);
  aggv[g * HID + cc]     = a0 * inv;
  aggv[g * HID + cc + 1] = a1 * inv;
}

// ---------------- small per-row projections on the 64 virtual nodes ----------------
__global__ void k_rowproj(const float* __restrict__ X, const float* __restrict__ W,
                          const float* __restrict__ bias, float* __restrict__ out) {
  __shared__ float xr[HID];
  int n = blockIdx.x, t = threadIdx.x;
  xr[t] = X[n * HID + t];
  __syncthreads();
  float s = bias[t];
  const float4* wr = (const float4*)(W + (size_t)t * HID);
  const float4* xx = (const float4*)xr;
  #pragma unroll 8
  for (int c = 0; c < HID / 4; ++c) {
    float4 w4 = wr[c], x4 = xx[c];
    s += x4.x * w4.x + x4.y * w4.y + x4.z * w4.z + x4.w * w4.w;
  }
  out[n * HID + t] = s;
}

__global__ void k_ov(const float* __restrict__ aggv, const float* __restrict__ Wa,
                     const float* __restrict__ ba, const float* __restrict__ skipv,
                     float* __restrict__ xv, float* __restrict__ outs) {
  __shared__ float xr[HID];
  int g = blockIdx.x, t = threadIdx.x;
  xr[t] = gelu_f(aggv[g * HID + t]);
  __syncthreads();
  float s = ba[t];
  const float4* wr = (const float4*)(Wa + (size_t)t * HID);
  const float4* xx = (const float4*)xr;
  #pragma unroll 8
  for (int c = 0; c < HID / 4; ++c) {
    float4 w4 = wr[c], x4 = xx[c];
    s += x4.x * w4.x + x4.y * w4.y + x4.z * w4.z + x4.w * w4.w;
  }
  float gg = sigmoid_f(*skipv);
  float nv2 = gg * s + (1.f - gg) * xv[g * HID + t];
  xv[g * HID + t] = nv2;
  outs[g * HID + t] = nv2;
}

// ---------------- JK attention + node/graph MLPs: one block per virtual node ----------------
struct TailW {
  const float *win, *bin, *wout, *bout;
  const float *nw0, *nb0, *nw1, *nb1, *nw2, *nb2, *nw3, *nb3, *nw4, *nb4, *nw5, *nb5, *nw6, *nb6;
  const float *gw0, *gb0, *gw1, *gb1;
};

__launch_bounds__(128)
__global__ void k_final(const float* __restrict__ outsv, TailW tw, float* __restrict__ outp) {
  __shared__ float xs[4][HID], qq[4][HID], kk[4][HID], vv[4][HID], oo[4][HID];
  __shared__ float att[NH][4][4];
  __shared__ float hb[HID], tb[64];
  int b = blockIdx.x, t = threadIdx.x;
  for (int l = 0; l < 4; ++l) xs[l][t] = outsv[(size_t)(l * NV + b) * HID + t];
  __syncthreads();
  for (int l = 0; l < 4; ++l) {
    float sq = tw.bin[t], sk = tw.bin[t + 128], sv = tw.bin[t + 256];
    const float* wq = tw.win + (size_t)t * HID;
    const float* wk = tw.win + (size_t)(t + 128) * HID;
    const float* wv = tw.win + (size_t)(t + 256) * HID;
    for (int c = 0; c < HID; ++c) {
      float x = xs[l][c];
      sq += x * wq[c]; sk += x * wk[c]; sv += x * wv[c];
    }
    qq[l][t] = sq; kk[l][t] = sk; vv[l][t] = sv;
  }
  __syncthreads();
  {
    int h = t >> 4, ql = (t >> 2) & 3, kl = t & 3;
    float s = 0.f;
    #pragma unroll
    for (int d = 0; d < DH; ++d) s += qq[ql][h * DH + d] * kk[kl][h * DH + d];
    att[h][ql][kl] = s * SCALE;
  }
  __syncthreads();
  if (t < 32) {
    int h = t >> 2, ql = t & 3;
    float m = att[h][ql][0];
    for (int k2 = 1; k2 < 4; ++k2) m = fmaxf(m, att[h][ql][k2]);
    float e[4], s = 0.f;
    for (int k2 = 0; k2 < 4; ++k2) { e[k2] = __expf(att[h][ql][k2] - m); s += e[k2]; }
    for (int k2 = 0; k2 < 4; ++k2) att[h][ql][k2] = e[k2] / s;
  }
  __syncthreads();
  {
    int h = t >> 4;
    #pragma unroll
    for (int ql = 0; ql < 4; ++ql) {
      float s = 0.f;
      #pragma unroll
      for (int kl = 0; kl < 4; ++kl) s += att[h][ql][kl] * vv[kl][t];
      oo[ql][t] = s;
    }
  }
  __syncthreads();
  {
    float s = 0.f;
    const float* wr = tw.wout + (size_t)t * HID;
    for (int l = 0; l < 4; ++l) {
      float ss = tw.bout[t];
      for (int c = 0; c < HID; ++c) ss += oo[l][c] * wr[c];
      s += ss;
    }
    hb[t] = s;
  }
  __syncthreads();
  if (t < 64) { float s = tw.nb0[t]; const float* wr = tw.nw0 + t * 128; for (int c = 0; c < 128; ++c) s += hb[c] * wr[c]; tb[t] = gelu_f(s); }
  __syncthreads();
  if (t < 32) { float s = tw.nb1[t]; const float* wr = tw.nw1 + t * 64;  for (int c = 0; c < 64;  ++c) s += tb[c] * wr[c]; hb[t] = gelu_f(s); }
  __syncthreads();
  if (t < 16) { float s = tw.nb2[t]; const float* wr = tw.nw2 + t * 32;  for (int c = 0; c < 32;  ++c) s += hb[c] * wr[c]; tb[t] = gelu_f(s); }
  __syncthreads();
  if (t < 8)  { float s = tw.nb3[t]; const float* wr = tw.nw3 + t * 16;  for (int c = 0; c < 16;  ++c) s += tb[c] * wr[c]; hb[t] = gelu_f(s); }
  __syncthreads();
  if (t < 4)  { float s = tw.nb4[t]; const float* wr = tw.nw4 + t * 8;   for (int c = 0; c < 8;   ++c) s += hb[c] * wr[c]; tb[t] = gelu_f(s); }
  __syncthreads();
  if (t < 2)  { float s = tw.nb5[t]; const float* wr = tw.nw5 + t * 4;   for (int c = 0; c < 4;   ++c) s += tb[c] * wr[c]; hb[t] = gelu_f(s); }
  __syncthreads();
  if (t == 0) {
    float s = hb[0] * tw.nw6[0] + hb[1] * tw.nw6[1] + tw.nb6[0];
    float g0 = gelu_f(s * tw.gw0[0] + tw.gb0[0]);
    float g1 = gelu_f(s * tw.gw0[1] + tw.gb0[1]);
    outp[b] = g0 * tw.gw1[0] + g1 * tw.gw1[1] + tw.gb1[0];
  }
}

// ---------------- host ----------------
extern "C" void kernel_launch(void* const* d_in, const int* in_sizes, int n_in,
                              void* d_out, int out_size, void* d_ws, size_t ws_size,
                              hipStream_t stream) {
  const float* x_op = (const float*)d_in[0];
  const float* x_v  = (const float*)d_in[1];
  const int*   ei0  = (const int*)d_in[2];
  const int*   ei1  = (const int*)d_in[3];
  const float* Wk   = (const float*)d_in[4];
  const float* Wq   = (const float*)d_in[5];
  const float* Wv   = (const float*)d_in[6];
  const float* Wa   = (const float*)d_in[7];
  const float* bk   = (const float*)d_in[8];
  const float* bq   = (const float*)d_in[9];
  const float* bv   = (const float*)d_in[10];
  const float* ba   = (const float*)d_in[11];
  const float* skip = (const float*)d_in[12];
  const float* a_rel = (const float*)d_in[13];
  const float* m_rel = (const float*)d_in[14];
  const float* p_rel = (const float*)d_in[15];
  (void)in_sizes; (void)n_in; (void)out_size; (void)ws_size;

  char* wsp = (char*)d_ws;
  size_t off = 0;
  auto alloc = [&](size_t bytes) -> void* {
    void* p = wsp + off;
    off += (bytes + 255) & ~(size_t)255;
    return p;
  };
  float* P     = (float*)alloc((size_t)NN * PST * 4);      // 83.9 MB
  float* xop   = (float*)alloc((size_t)NN * HID * 4);      // 16.8 MB
  float* agg   = (float*)alloc((size_t)NN * HID * 4);      // 16.8 MB
  float* CW    = (float*)alloc((size_t)16 * HID * HID * 4);
  float* CB    = (float*)alloc((size_t)16 * HID * 4);
  float* WqT   = (float*)alloc((size_t)NL * HID * HID * 4);
  float* WaT   = (float*)alloc((size_t)NL * HID * HID * 4);
  float* xv    = (float*)alloc((size_t)NV * HID * 4);
  float* qv    = (float*)alloc((size_t)NV * HID * 4);
  float* aggv  = (float*)alloc((size_t)NV * HID * 4);
  float* outsv = (float*)alloc((size_t)NL * NV * HID * 4);
  float* part  = (float*)alloc((size_t)NV * 32 * 192 * 4); // 1.57 MB edge1 partials
  int* rowptr0 = (int*)alloc((size_t)(NN + 1) * 4);
  int* cur0    = (int*)alloc((size_t)NN * 4);
  int* col0    = (int*)alloc((size_t)E0E * 4);
  int* rowptr1 = (int*)alloc((size_t)(NV + 1) * 4);
  int* cur1    = (int*)alloc((size_t)NV * 4);
  int* col1    = (int*)alloc((size_t)NN * 4);

  // CSR build (ws is re-poisoned each call, so rebuild every time)
  k_zero<<<NN / 256, 256, 0, stream>>>(cur0, cur1);
  k_hist<<<E0E / 256, 256, 0, stream>>>(ei0 + E0E, E0E, cur0);
  k_hist<<<NN / 256, 256, 0, stream>>>(ei1 + NN, NN, cur1);
  k_scan<1024, 32><<<1, 1024, 0, stream>>>(cur0, rowptr0, E0E, NN);
  k_scan<64, 1><<<1, 64, 0, stream>>>(cur1, rowptr1, NN, NV);
  k_scatter<<<E0E / 256, 256, 0, stream>>>(ei0, ei0 + E0E, E0E, cur0, col0);
  k_scatter<<<NN / 256, 256, 0, stream>>>(ei1, ei1 + NN, NN, cur1, col1);
  k_copy4<<<(NN * HID / 4 + 255) / 256, 256, 0, stream>>>((const float4*)x_op, (float4*)xop, NN * HID / 4);
  k_copy4<<<(NV * HID / 4 + 255) / 256, 256, 0, stream>>>((const float4*)x_v, (float4*)xv, NV * HID / 4);
  k_combine<<<16, 256, 0, stream>>>(Wk, Wv, bk, bv, a_rel, m_rel, p_rel, CW, CB);
  k_transp<<<dim3(4, 2), 256, 0, stream>>>(Wq, Wa, WqT, WaT);

  for (int l = 0; l < NL; ++l) {
    WSet wp;
    wp.w[0] = WqT + (size_t)l * HID * HID;  wp.b[0] = bq + (l * 2 + 0) * HID;
    for (int m = 0; m < 4; ++m) {
      wp.w[1 + m] = CW + (size_t)(l * 4 + m) * HID * HID;
      wp.b[1 + m] = CB + (l * 4 + m) * HID;
    }
    // P = xop @ [Wq | kv0(lo) | kv0(hi) | kv1(lo) | kv1(hi)]  (interleaved kv cols)
    k_gemm<<<dim3(NN / 64, 5), 256, 0, stream>>>(xop, HID, wp, P, PST, 0, nullptr);
    k_rowproj<<<NV, HID, 0, stream>>>(xv, Wq + (size_t)(l * 2 + 1) * HID * HID,
                                      bq + (l * 2 + 1) * HID, qv);
    k_edge0<<<NN / 4 * NH, 256, 0, stream>>>(P, rowptr0, col0, agg);
    k_edge1<<<NV * 8, 256, 0, stream>>>(P, qv, rowptr1, col1, part);
    k_edge1red<<<NV, 64, 0, stream>>>(part, aggv);
    WSet wo;
    wo.w[0] = WaT + (size_t)l * HID * HID; wo.b[0] = ba + (l * 2 + 0) * HID;
    for (int m = 1; m < 5; ++m) { wo.w[m] = wo.w[0]; wo.b[m] = wo.b[0]; }
    // xop = g*(gelu(agg) @ Wa^T + ba) + (1-g)*xop
    k_gemm<<<dim3(NN / 64, 1), 256, 0, stream>>>(agg, HID, wo, xop, HID, 1, skip + l * 2 + 0);
    k_ov<<<NV, HID, 0, stream>>>(aggv, Wa + (size_t)(l * 2 + 1) * HID * HID,
                                 ba + (l * 2 + 1) * HID, skip + l * 2 + 1,
                                 xv, outsv + (size_t)l * NV * HID);
  }

  TailW tw;
  tw.win  = (const float*)d_in[16]; tw.bin  = (const float*)d_in[17];
  tw.wout = (const float*)d_in[18]; tw.bout = (const float*)d_in[19];
  tw.nw0 = (const float*)d_in[20]; tw.nb0 = (const float*)d_in[21];
  tw.nw1 = (const float*)d_in[22]; tw.nb1 = (const float*)d_in[23];
  tw.nw2 = (const float*)d_in[24]; tw.nb2 = (const float*)d_in[25];
  tw.nw3 = (const float*)d_in[26]; tw.nb3 = (const float*)d_in[27];
  tw.nw4 = (const float*)d_in[28]; tw.nb4 = (const float*)d_in[29];
  tw.nw5 = (const float*)d_in[30]; tw.nb5 = (const float*)d_in[31];
  tw.nw6 = (const float*)d_in[32]; tw.nb6 = (const float*)d_in[33];
  tw.gw0 = (const float*)d_in[34]; tw.gb0 = (const float*)d_in[35];
  tw.gw1 = (const float*)d_in[36]; tw.gb1 = (const float*)d_in[37];
  k_final<<<NV, HID, 0, stream>>>(outsv, tw, (float*)d_out);
}

// Round 8
// 1014.818 us; speedup vs baseline: 1.2971x; 1.2416x over previous
//
#include <hip/hip_runtime.h>

#define NN   32768
#define NV   64
#define E0E  524288
#define HID  128
#define NL   4
#define NH   8
#define DH   16
#define SCALE 0.25f
#define PST  640   // P row stride: [q | k0 | v0 | k1 | v1]  (r5 layout)

__device__ __forceinline__ float gelu_f(float x) {
  return 0.5f * x * (1.0f + erff(x * 0.7071067811865475f));
}
__device__ __forceinline__ float sigmoid_f(float x) {
  return 1.0f / (1.0f + __expf(-x));
}

struct WSet { const float* w[5]; const float* b[5]; };

// ================= fused setup #1: zero + copies + weight-combine + weight-transpose ==========
// blocks: [0,128) zero | [128,4224) copy xop | [4224,4232) copy xv | [4232,4248) combine
//         | [4248,4256) transp
__global__ __launch_bounds__(256) void k_setup1(
    int* __restrict__ cur0, int* __restrict__ cur1,
    const float4* __restrict__ x_op4, float4* __restrict__ xop4,
    const float4* __restrict__ x_v4, float4* __restrict__ xv4,
    const float* __restrict__ Wk, const float* __restrict__ Wv,
    const float* __restrict__ bk, const float* __restrict__ bv,
    const float* __restrict__ a_rel, const float* __restrict__ m_rel,
    const float* __restrict__ p_rel,
    float* __restrict__ CW, float* __restrict__ CB,
    const float* __restrict__ Wq, const float* __restrict__ Wa,
    float* __restrict__ WqT, float* __restrict__ WaT) {
  int b = blockIdx.x, t = threadIdx.x;
  if (b < 128) { int i = b * 256 + t; cur0[i] = 0; if (i < NV) cur1[i] = 0; return; }
  b -= 128;
  if (b < 4096) { xop4[b * 256 + t] = x_op4[b * 256 + t]; return; }
  b -= 4096;
  if (b < 8) { xv4[b * 256 + t] = x_v4[b * 256 + t]; return; }
  b -= 8;
  if (b < 16) {
    // combine: CW[blk][k][j] (transposed [k][n]); blk = l*4+mat
    int blk = b;
    int l = blk >> 2, mat = blk & 3;
    int rel = mat >> 1;
    int isK = ((mat & 1) == 0);
    const float* W  = (isK ? Wk : Wv) + (size_t)(l * 2) * HID * HID;
    const float* bb = (isK ? bk : bv) + (l * 2) * HID;
    const float* R  = (isK ? a_rel : m_rel) + (size_t)((l * 2 + rel) * NH) * DH * DH;
    float* cw = CW + (size_t)blk * HID * HID;
    float* cb = CB + blk * HID;
    for (int o = t; o < HID * HID; o += 256) {
      int j = o >> 7, c = o & 127;
      int h = j >> 4, e = j & 15;
      float sc = isK ? (p_rel[(l * 2 + rel) * NH + h] * SCALE) : 1.0f;
      float s = 0.f;
      #pragma unroll
      for (int d = 0; d < DH; ++d)
        s += W[(size_t)(h * DH + d) * HID + c] * R[h * 256 + d * 16 + e];
      cw[(size_t)c * HID + j] = s * sc;   // [k][n]
    }
    if (t < HID) {
      int j = t, h = j >> 4, e = j & 15;
      float sc = isK ? (p_rel[(l * 2 + rel) * NH + h] * SCALE) : 1.0f;
      float s = 0.f;
      #pragma unroll
      for (int d = 0; d < DH; ++d) s += bb[h * DH + d] * R[h * 256 + d * 16 + e];
      cb[j] = s * sc;
    }
    return;
  }
  b -= 16;
  {  // transp: idx 0..7 -> l = idx>>1, which = idx&1
    int l = b >> 1;
    const float* src = ((b & 1) == 0 ? Wq : Wa) + (size_t)(l * 2) * HID * HID;
    float*       dst = ((b & 1) == 0 ? WqT : WaT) + (size_t)l * HID * HID;
    for (int o = t; o < HID * HID; o += 256) {
      int n = o >> 7, k = o & 127;
      dst[(size_t)k * HID + n] = src[o];
    }
  }
}

// ================= fused setup #2: both histograms ============================================
__global__ __launch_bounds__(256) void k_hist2(const int* __restrict__ dst0,
                                               const int* __restrict__ dst1,
                                               int* __restrict__ cur0, int* __restrict__ cur1) {
  int b = blockIdx.x, t = threadIdx.x;
  if (b < E0E / 256) { atomicAdd(&cur0[dst0[b * 256 + t]], 1); }
  else { atomicAdd(&cur1[dst1[(b - E0E / 256) * 256 + t]], 1); }
}

// ================= fused setup #3: both scans =================================================
__global__ __launch_bounds__(1024) void k_scan2(int* __restrict__ cnt0, int* __restrict__ rp0,
                                                int* __restrict__ cnt1, int* __restrict__ rp1) {
  __shared__ int sd[1024];
  int t = threadIdx.x;
  if (blockIdx.x == 0) {
    int loc[32];
    int base = t * 32, s = 0;
    #pragma unroll
    for (int i = 0; i < 32; ++i) { loc[i] = cnt0[base + i]; s += loc[i]; }
    sd[t] = s;
    __syncthreads();
    for (int off = 1; off < 1024; off <<= 1) {
      int v = (t >= off) ? sd[t - off] : 0;
      __syncthreads();
      sd[t] += v;
      __syncthreads();
    }
    int run = sd[t] - s;
    #pragma unroll
    for (int i = 0; i < 32; ++i) { rp0[base + i] = run; cnt0[base + i] = run; run += loc[i]; }
    if (t == 1023) rp0[NN] = E0E;
  } else if (t < 64) {
    int v = cnt1[t];
    int s = v;
    #pragma unroll
    for (int off = 1; off < 64; off <<= 1) {
      int u = __shfl_up(s, off);
      if (t >= off) s += u;
    }
    int ex = s - v;
    rp1[t] = ex; cnt1[t] = ex;
    if (t == 63) rp1[NV] = NN;
  }
}

// ================= fused setup #4: both scatters ==============================================
__global__ __launch_bounds__(256) void k_scat2(const int* __restrict__ src0,
                                               const int* __restrict__ dst0,
                                               int* __restrict__ cur0, int* __restrict__ col0,
                                               const int* __restrict__ src1,
                                               const int* __restrict__ dst1,
                                               int* __restrict__ cur1, int* __restrict__ col1) {
  int b = blockIdx.x, t = threadIdx.x;
  if (b < E0E / 256) {
    int e = b * 256 + t;
    int pos = atomicAdd(&cur0[dst0[e]], 1);
    col0[pos] = src0[e];
  } else {
    int e = (b - E0E / 256) * 256 + t;
    int pos = atomicAdd(&cur1[dst1[e]], 1);
    col1[pos] = src1[e];
  }
}

// ================= k_proj: 5-matrix GEMM (y=0..4) + virtual-q rowproj (y=5) ===================
// GEMM: BM=64, BN=128, BK=32, 256 threads, 4x8 micro-tile (r5 config).
__launch_bounds__(256)
__global__ void k_proj(const float* __restrict__ A, WSet ws, float* __restrict__ P,
                       const float* __restrict__ rpW, const float* __restrict__ rpB,
                       const float* __restrict__ rpX, float* __restrict__ qvout) {
  __shared__ float As[64][36];
  __shared__ float Bs[32][132];
  const int t = threadIdx.x;
  if (blockIdx.y == 5) {           // rowproj tail: qv = xv @ Wq[l,1]^T + bq
    __shared__ float xr[HID];
    int n = blockIdx.x;
    if (n >= NV) return;
    if (t < HID) xr[t] = rpX[n * HID + t];
    __syncthreads();
    if (t < HID) {
      float s = rpB[t];
      const float4* wr = (const float4*)(rpW + (size_t)t * HID);
      const float4* xx = (const float4*)xr;
      #pragma unroll 8
      for (int c = 0; c < HID / 4; ++c) {
        float4 w4 = wr[c], x4 = xx[c];
        s += x4.x * w4.x + x4.y * w4.y + x4.z * w4.z + x4.w * w4.w;
      }
      qvout[n * HID + t] = s;
    }
    return;
  }
  const float* __restrict__ WT   = ws.w[blockIdx.y];   // [k][n]
  const float* __restrict__ bias = ws.b[blockIdx.y];
  const int m0 = blockIdx.x * 64;
  const int tx = t & 15, ty = t >> 4;
  const int sm = t >> 3;
  const int sk = (t & 7) * 4;
  const int bk = t >> 5;
  const int bc = (t & 31) * 4;
  float acc[4][8] = {};
  for (int kt = 0; kt < HID; kt += 32) {
    #pragma unroll
    for (int p = 0; p < 2; ++p) {
      int m = sm + p * 32;
      *(float4*)&As[m][sk] = *(const float4*)(A + (size_t)(m0 + m) * HID + kt + sk);
    }
    #pragma unroll
    for (int p = 0; p < 4; ++p) {
      int kk = bk + p * 8;
      *(float4*)&Bs[kk][bc] = *(const float4*)(WT + (size_t)(kt + kk) * HID + bc);
    }
    __syncthreads();
    #pragma unroll
    for (int k4 = 0; k4 < 32; k4 += 4) {
      float4 a4[4];
      #pragma unroll
      for (int r = 0; r < 4; ++r) a4[r] = *(const float4*)&As[4 * ty + r][k4];
      #pragma unroll
      for (int j = 0; j < 4; ++j) {
        float4 b0 = *(const float4*)&Bs[k4 + j][4 * tx];
        float4 b1 = *(const float4*)&Bs[k4 + j][64 + 4 * tx];
        #pragma unroll
        for (int i = 0; i < 4; ++i) {
          float ai = ((const float*)&a4[i])[j];
          acc[i][0] += ai * b0.x; acc[i][1] += ai * b0.y;
          acc[i][2] += ai * b0.z; acc[i][3] += ai * b0.w;
          acc[i][4] += ai * b1.x; acc[i][5] += ai * b1.y;
          acc[i][6] += ai * b1.z; acc[i][7] += ai * b1.w;
        }
      }
    }
    __syncthreads();
  }
  const int cbase = blockIdx.y * HID;
  #pragma unroll
  for (int i = 0; i < 4; ++i) {
    int m = m0 + 4 * ty + i;
    float* po = P + (size_t)m * PST + cbase;
    #pragma unroll
    for (int hh = 0; hh < 2; ++hh) {
      int c = hh * 64 + 4 * tx;
      float4 bb = *(const float4*)(bias + c);
      float4 o;
      o.x = acc[i][hh * 4 + 0] + bb.x; o.y = acc[i][hh * 4 + 1] + bb.y;
      o.z = acc[i][hh * 4 + 2] + bb.z; o.w = acc[i][hh * 4 + 3] + bb.w;
      *(float4*)(po + c) = o;
    }
  }
}

// ================= k_edges: edge0 (blocks < NN/4) + edge1 (NN/4 .. NN/4+512) ==================
__launch_bounds__(256)
__global__ void k_edges(const float* __restrict__ P, const int* __restrict__ rowptr0,
                        const int* __restrict__ col0, float* __restrict__ agg,
                        const float* __restrict__ qv, const int* __restrict__ rowptr1,
                        const int* __restrict__ col1, float* __restrict__ part) {
  int lane = threadIdx.x & 63;
  if (blockIdx.x < NN / 4) {
    // ---- relation 0: one wave per dst node, full row, unroll-8 (r5 form) ----
    int n = blockIdx.x * 4 + (threadIdx.x >> 6);
    float2 q = *(const float2*)(P + (size_t)n * PST + 2 * lane);
    int e0 = rowptr0[n], e1 = rowptr0[n + 1];
    float acc0 = 0.f, acc1 = 0.f, wsum = 0.f;
    int e = e0;
    for (; e + 8 <= e1; e += 8) {
      const float* r[8];
      #pragma unroll
      for (int u = 0; u < 8; ++u) r[u] = P + (size_t)col0[e + u] * PST + 2 * lane;
      float2 kx[8], vx[8];
      #pragma unroll
      for (int u = 0; u < 8; ++u) kx[u] = *(const float2*)(r[u] + 128);
      #pragma unroll
      for (int u = 0; u < 8; ++u) vx[u] = *(const float2*)(r[u] + 256);
      float p[8];
      #pragma unroll
      for (int u = 0; u < 8; ++u) p[u] = q.x * kx[u].x + q.y * kx[u].y;
      #pragma unroll
      for (int u = 0; u < 8; ++u) {
        p[u] += __shfl_xor(p[u], 1); p[u] += __shfl_xor(p[u], 2); p[u] += __shfl_xor(p[u], 4);
      }
      #pragma unroll
      for (int u = 0; u < 8; ++u) {
        float w = __expf(p[u]);
        wsum += w; acc0 += w * vx[u].x; acc1 += w * vx[u].y;
      }
    }
    for (; e < e1; ++e) {
      const float* row = P + (size_t)col0[e] * PST + 2 * lane;
      float2 kv = *(const float2*)(row + 128);
      float p = q.x * kv.x + q.y * kv.y;
      p += __shfl_xor(p, 1); p += __shfl_xor(p, 2); p += __shfl_xor(p, 4);
      float w = __expf(p);
      float2 vv = *(const float2*)(row + 256);
      wsum += w; acc0 += w * vv.x; acc1 += w * vv.y;
    }
    float inv = 1.0f / (wsum + 1e-16f);
    *(float2*)(agg + (size_t)n * HID + 2 * lane) = make_float2(acc0 * inv, acc1 * inv);
  } else {
    // ---- relation 1: 8 chunk-blocks per virtual node, per-wave partials (r5 form) ----
    int b2 = blockIdx.x - NN / 4;
    int g = b2 >> 3, ch = b2 & 7;
    int w = threadIdx.x >> 6;
    int slot = ch * 4 + w;
    float2 q = *(const float2*)(qv + g * HID + 2 * lane);
    int e0 = rowptr1[g], e1 = rowptr1[g + 1];
    int tot = e1 - e0;
    int len = (tot + 31) >> 5;
    int s0 = e0 + slot * len;
    int s1 = s0 + len; if (s1 > e1) s1 = e1;
    float acc0 = 0.f, acc1 = 0.f, wsum = 0.f;
    int e = s0;
    for (; e + 4 <= s1; e += 4) {
      const float* ra = P + (size_t)col1[e]     * PST + 2 * lane;
      const float* rb = P + (size_t)col1[e + 1] * PST + 2 * lane;
      const float* rc = P + (size_t)col1[e + 2] * PST + 2 * lane;
      const float* rd = P + (size_t)col1[e + 3] * PST + 2 * lane;
      float2 ka = *(const float2*)(ra + 384);
      float2 kb = *(const float2*)(rb + 384);
      float2 kc = *(const float2*)(rc + 384);
      float2 kd = *(const float2*)(rd + 384);
      float2 va = *(const float2*)(ra + 512);
      float2 vb = *(const float2*)(rb + 512);
      float2 vc = *(const float2*)(rc + 512);
      float2 vd = *(const float2*)(rd + 512);
      float pa = q.x * ka.x + q.y * ka.y;
      float pb = q.x * kb.x + q.y * kb.y;
      float pc = q.x * kc.x + q.y * kc.y;
      float pd = q.x * kd.x + q.y * kd.y;
      pa += __shfl_xor(pa, 1); pb += __shfl_xor(pb, 1); pc += __shfl_xor(pc, 1); pd += __shfl_xor(pd, 1);
      pa += __shfl_xor(pa, 2); pb += __shfl_xor(pb, 2); pc += __shfl_xor(pc, 2); pd += __shfl_xor(pd, 2);
      pa += __shfl_xor(pa, 4); pb += __shfl_xor(pb, 4); pc += __shfl_xor(pc, 4); pd += __shfl_xor(pd, 4);
      float wa = __expf(pa), wb = __expf(pb), wc = __expf(pc), wd = __expf(pd);
      wsum += (wa + wb) + (wc + wd);
      acc0 += wa * va.x + wb * vb.x + wc * vc.x + wd * vd.x;
      acc1 += wa * va.y + wb * vb.y + wc * vc.y + wd * vd.y;
    }
    for (; e < s1; ++e) {
      const float* row = P + (size_t)col1[e] * PST + 2 * lane;
      float2 kv = *(const float2*)(row + 384);
      float p = q.x * kv.x + q.y * kv.y;
      p += __shfl_xor(p, 1); p += __shfl_xor(p, 2); p += __shfl_xor(p, 4);
      float ww = __expf(p);
      float2 vv = *(const float2*)(row + 512);
      wsum += ww; acc0 += ww * vv.x; acc1 += ww * vv.y;
    }
    float* pp = part + (size_t)(g * 32 + slot) * 192;
    pp[lane] = acc0; pp[64 + lane] = acc1; pp[128 + lane] = wsum;
  }
}

// ================= k_post: out-GEMM with gelu+skip (blocks<512) + vnode tail (512..575) =======
__launch_bounds__(256)
__global__ void k_post(const float* __restrict__ A, const float* __restrict__ WT,
                       const float* __restrict__ bias, const float* __restrict__ skipv,
                       float* __restrict__ out,
                       const float* __restrict__ part, const float* __restrict__ Wa1,
                       const float* __restrict__ ba1, const float* __restrict__ skip1,
                       float* __restrict__ xv, float* __restrict__ outs) {
  __shared__ float As[64][36];
  __shared__ float Bs[32][132];
  const int t = threadIdx.x;
  if (blockIdx.x >= NN / 64) {
    // ---- vnode tail: edge1red + gelu + Wa[l,1] proj + sigmoid skip ----
    __shared__ float xr[HID];
    int v = blockIdx.x - NN / 64;
    if (t < 64) {
      float a0 = 0.f, a1 = 0.f, ws2 = 0.f;
      for (int s = 0; s < 32; ++s) {
        const float* p = part + (size_t)(v * 32 + s) * 192;
        a0 += p[t]; a1 += p[64 + t]; ws2 += p[128 + t];
      }
      float inv = 1.0f / (ws2 + 1e-16f);
      xr[2 * t]     = gelu_f(a0 * inv);
      xr[2 * t + 1] = gelu_f(a1 * inv);
    }
    __syncthreads();
    if (t < HID) {
      float s = ba1[t];
      const float4* wr = (const float4*)(Wa1 + (size_t)t * HID);
      const float4* xx = (const float4*)xr;
      #pragma unroll 8
      for (int c = 0; c < HID / 4; ++c) {
        float4 w4 = wr[c], x4 = xx[c];
        s += x4.x * w4.x + x4.y * w4.y + x4.z * w4.z + x4.w * w4.w;
      }
      float gg = sigmoid_f(*skip1);
      float nv2 = gg * s + (1.f - gg) * xv[v * HID + t];
      xv[v * HID + t] = nv2;
      outs[v * HID + t] = nv2;
    }
    return;
  }
  const int m0 = blockIdx.x * 64;
  const int tx = t & 15, ty = t >> 4;
  const int sm = t >> 3;
  const int sk = (t & 7) * 4;
  const int bk = t >> 5;
  const int bc = (t & 31) * 4;
  float acc[4][8] = {};
  for (int kt = 0; kt < HID; kt += 32) {
    #pragma unroll
    for (int p = 0; p < 2; ++p) {
      int m = sm + p * 32;
      float4 av = *(const float4*)(A + (size_t)(m0 + m) * HID + kt + sk);
      av.x = gelu_f(av.x); av.y = gelu_f(av.y); av.z = gelu_f(av.z); av.w = gelu_f(av.w);
      *(float4*)&As[m][sk] = av;
    }
    #pragma unroll
    for (int p = 0; p < 4; ++p) {
      int kk = bk + p * 8;
      *(float4*)&Bs[kk][bc] = *(const float4*)(WT + (size_t)(kt + kk) * HID + bc);
    }
    __syncthreads();
    #pragma unroll
    for (int k4 = 0; k4 < 32; k4 += 4) {
      float4 a4[4];
      #pragma unroll
      for (int r = 0; r < 4; ++r) a4[r] = *(const float4*)&As[4 * ty + r][k4];
      #pragma unroll
      for (int j = 0; j < 4; ++j) {
        float4 b0 = *(const float4*)&Bs[k4 + j][4 * tx];
        float4 b1 = *(const float4*)&Bs[k4 + j][64 + 4 * tx];
        #pragma unroll
        for (int i = 0; i < 4; ++i) {
          float ai = ((const float*)&a4[i])[j];
          acc[i][0] += ai * b0.x; acc[i][1] += ai * b0.y;
          acc[i][2] += ai * b0.z; acc[i][3] += ai * b0.w;
          acc[i][4] += ai * b1.x; acc[i][5] += ai * b1.y;
          acc[i][6] += ai * b1.z; acc[i][7] += ai * b1.w;
        }
      }
    }
    __syncthreads();
  }
  float g = sigmoid_f(*skipv), gm1 = 1.0f - g;
  #pragma unroll
  for (int i = 0; i < 4; ++i) {
    int m = m0 + 4 * ty + i;
    float* po = out + (size_t)m * HID;
    #pragma unroll
    for (int hh = 0; hh < 2; ++hh) {
      int c = hh * 64 + 4 * tx;
      float4 bb = *(const float4*)(bias + c);
      float4 o;
      o.x = acc[i][hh * 4 + 0] + bb.x; o.y = acc[i][hh * 4 + 1] + bb.y;
      o.z = acc[i][hh * 4 + 2] + bb.z; o.w = acc[i][hh * 4 + 3] + bb.w;
      float* qp = po + c;
      float4 xo = *(const float4*)qp;   // out aliases old-x (read-before-write, same elem)
      o.x = g * o.x + gm1 * xo.x; o.y = g * o.y + gm1 * xo.y;
      o.z = g * o.z + gm1 * xo.z; o.w = g * o.w + gm1 * xo.w;
      *(float4*)qp = o;
    }
  }
}

// ================= JK attention + node/graph MLPs: one block per virtual node =================
struct TailW {
  const float *win, *bin, *wout, *bout;
  const float *nw0, *nb0, *nw1, *nb1, *nw2, *nb2, *nw3, *nb3, *nw4, *nb4, *nw5, *nb5, *nw6, *nb6;
  const float *gw0, *gb0, *gw1, *gb1;
};

__launch_bounds__(128)
__global__ void k_final(const float* __restrict__ outsv, TailW tw, float* __restrict__ outp) {
  __shared__ float xs[4][HID], qq[4][HID], kk[4][HID], vv[4][HID], oo[4][HID];
  __shared__ float att[NH][4][4];
  __shared__ float hb[HID], tb[64];
  int b = blockIdx.x, t = threadIdx.x;
  for (int l = 0; l < 4; ++l) xs[l][t] = outsv[(size_t)(l * NV + b) * HID + t];
  __syncthreads();
  for (int l = 0; l < 4; ++l) {
    float sq = tw.bin[t], sk = tw.bin[t + 128], sv = tw.bin[t + 256];
    const float* wq = tw.win + (size_t)t * HID;
    const float* wk = tw.win + (size_t)(t + 128) * HID;
    const float* wv = tw.win + (size_t)(t + 256) * HID;
    for (int c = 0; c < HID; ++c) {
      float x = xs[l][c];
      sq += x * wq[c]; sk += x * wk[c]; sv += x * wv[c];
    }
    qq[l][t] = sq; kk[l][t] = sk; vv[l][t] = sv;
  }
  __syncthreads();
  {
    int h = t >> 4, ql = (t >> 2) & 3, kl = t & 3;
    float s = 0.f;
    #pragma unroll
    for (int d = 0; d < DH; ++d) s += qq[ql][h * DH + d] * kk[kl][h * DH + d];
    att[h][ql][kl] = s * SCALE;
  }
  __syncthreads();
  if (t < 32) {
    int h = t >> 2, ql = t & 3;
    float m = att[h][ql][0];
    for (int k2 = 1; k2 < 4; ++k2) m = fmaxf(m, att[h][ql][k2]);
    float e[4], s = 0.f;
    for (int k2 = 0; k2 < 4; ++k2) { e[k2] = __expf(att[h][ql][k2] - m); s += e[k2]; }
    for (int k2 = 0; k2 < 4; ++k2) att[h][ql][k2] = e[k2] / s;
  }
  __syncthreads();
  {
    int h = t >> 4;
    #pragma unroll
    for (int ql = 0; ql < 4; ++ql) {
      float s = 0.f;
      #pragma unroll
      for (int kl = 0; kl < 4; ++kl) s += att[h][ql][kl] * vv[kl][t];
      oo[ql][t] = s;
    }
  }
  __syncthreads();
  {
    float s = 0.f;
    const float* wr = tw.wout + (size_t)t * HID;
    for (int l = 0; l < 4; ++l) {
      float ss = tw.bout[t];
      for (int c = 0; c < HID; ++c) ss += oo[l][c] * wr[c];
      s += ss;
    }
    hb[t] = s;
  }
  __syncthreads();
  if (t < 64) { float s = tw.nb0[t]; const float* wr = tw.nw0 + t * 128; for (int c = 0; c < 128; ++c) s += hb[c] * wr[c]; tb[t] = gelu_f(s); }
  __syncthreads();
  if (t < 32) { float s = tw.nb1[t]; const float* wr = tw.nw1 + t * 64;  for (int c = 0; c < 64;  ++c) s += tb[c] * wr[c]; hb[t] = gelu_f(s); }
  __syncthreads();
  if (t < 16) { float s = tw.nb2[t]; const float* wr = tw.nw2 + t * 32;  for (int c = 0; c < 32;  ++c) s += hb[c] * wr[c]; tb[t] = gelu_f(s); }
  __syncthreads();
  if (t < 8)  { float s = tw.nb3[t]; const float* wr = tw.nw3 + t * 16;  for (int c = 0; c < 16;  ++c) s += tb[c] * wr[c]; hb[t] = gelu_f(s); }
  __syncthreads();
  if (t < 4)  { float s = tw.nb4[t]; const float* wr = tw.nw4 + t * 8;   for (int c = 0; c < 8;   ++c) s += hb[c] * wr[c]; tb[t] = gelu_f(s); }
  __syncthreads();
  if (t < 2)  { float s = tw.nb5[t]; const float* wr = tw.nw5 + t * 4;   for (int c = 0; c < 4;   ++c) s += tb[c] * wr[c]; hb[t] = gelu_f(s); }
  __syncthreads();
  if (t == 0) {
    float s = hb[0] * tw.nw6[0] + hb[1] * tw.nw6[1] + tw.nb6[0];
    float g0 = gelu_f(s * tw.gw0[0] + tw.gb0[0]);
    float g1 = gelu_f(s * tw.gw0[1] + tw.gb0[1]);
    outp[b] = g0 * tw.gw1[0] + g1 * tw.gw1[1] + tw.gb1[0];
  }
}

// ================= host =======================================================================
extern "C" void kernel_launch(void* const* d_in, const int* in_sizes, int n_in,
                              void* d_out, int out_size, void* d_ws, size_t ws_size,
                              hipStream_t stream) {
  const float* x_op = (const float*)d_in[0];
  const float* x_v  = (const float*)d_in[1];
  const int*   ei0  = (const int*)d_in[2];
  const int*   ei1  = (const int*)d_in[3];
  const float* Wk   = (const float*)d_in[4];
  const float* Wq   = (const float*)d_in[5];
  const float* Wv   = (const float*)d_in[6];
  const float* Wa   = (const float*)d_in[7];
  const float* bk   = (const float*)d_in[8];
  const float* bq   = (const float*)d_in[9];
  const float* bv   = (const float*)d_in[10];
  const float* ba   = (const float*)d_in[11];
  const float* skip = (const float*)d_in[12];
  const float* a_rel = (const float*)d_in[13];
  const float* m_rel = (const float*)d_in[14];
  const float* p_rel = (const float*)d_in[15];
  (void)in_sizes; (void)n_in; (void)out_size; (void)ws_size;

  char* wsp = (char*)d_ws;
  size_t off = 0;
  auto alloc = [&](size_t bytes) -> void* {
    void* p = wsp + off;
    off += (bytes + 255) & ~(size_t)255;
    return p;
  };
  float* P     = (float*)alloc((size_t)NN * PST * 4);
  float* xop   = (float*)alloc((size_t)NN * HID * 4);
  float* agg   = (float*)alloc((size_t)NN * HID * 4);
  float* CW    = (float*)alloc((size_t)16 * HID * HID * 4);
  float* CB    = (float*)alloc((size_t)16 * HID * 4);
  float* WqT   = (float*)alloc((size_t)NL * HID * HID * 4);
  float* WaT   = (float*)alloc((size_t)NL * HID * HID * 4);
  float* xv    = (float*)alloc((size_t)NV * HID * 4);
  float* qv    = (float*)alloc((size_t)NV * HID * 4);
  float* outsv = (float*)alloc((size_t)NL * NV * HID * 4);
  float* part  = (float*)alloc((size_t)NV * 32 * 192 * 4);
  int* rowptr0 = (int*)alloc((size_t)(NN + 1) * 4);
  int* cur0    = (int*)alloc((size_t)NN * 4);
  int* col0    = (int*)alloc((size_t)E0E * 4);
  int* rowptr1 = (int*)alloc((size_t)(NV + 1) * 4);
  int* cur1    = (int*)alloc((size_t)NV * 4);
  int* col1    = (int*)alloc((size_t)NN * 4);

  // fused setup: 4 launches (ws re-poisoned every call -> rebuild each time)
  k_setup1<<<4256, 256, 0, stream>>>(cur0, cur1,
                                     (const float4*)x_op, (float4*)xop,
                                     (const float4*)x_v, (float4*)xv,
                                     Wk, Wv, bk, bv, a_rel, m_rel, p_rel,
                                     CW, CB, Wq, Wa, WqT, WaT);
  k_hist2<<<E0E / 256 + NN / 256, 256, 0, stream>>>(ei0 + E0E, ei1 + NN, cur0, cur1);
  k_scan2<<<2, 1024, 0, stream>>>(cur0, rowptr0, cur1, rowptr1);
  k_scat2<<<E0E / 256 + NN / 256, 256, 0, stream>>>(ei0, ei0 + E0E, cur0, col0,
                                                    ei1, ei1 + NN, cur1, col1);

  for (int l = 0; l < NL; ++l) {
    WSet wp;
    wp.w[0] = WqT + (size_t)l * HID * HID;  wp.b[0] = bq + (l * 2 + 0) * HID;
    for (int m = 0; m < 4; ++m) {
      wp.w[1 + m] = CW + (size_t)(l * 4 + m) * HID * HID;
      wp.b[1 + m] = CB + (l * 4 + m) * HID;
    }
    // P = xop @ [Wq | Wk*a0 | Wv*m0 | Wk*a1 | Wv*m1]^T  +  qv = xv @ Wq[l,1]^T (y=5)
    k_proj<<<dim3(NN / 64, 6), 256, 0, stream>>>(xop, wp, P,
                                                 Wq + (size_t)(l * 2 + 1) * HID * HID,
                                                 bq + (l * 2 + 1) * HID, xv, qv);
    // edge0 + edge1 in one launch
    k_edges<<<NN / 4 + NV * 8, 256, 0, stream>>>(P, rowptr0, col0, agg, qv, rowptr1, col1, part);
    // out-GEMM (+skip) and vnode tail (edge1red + out-proj + skip) in one launch
    k_post<<<NN / 64 + NV, 256, 0, stream>>>(agg, WaT + (size_t)l * HID * HID,
                                             ba + (l * 2 + 0) * HID, skip + l * 2 + 0, xop,
                                             part, Wa + (size_t)(l * 2 + 1) * HID * HID,
                                             ba + (l * 2 + 1) * HID, skip + l * 2 + 1,
                                             xv, outsv + (size_t)l * NV * HID);
  }

  TailW tw;
  tw.win  = (const float*)d_in[16]; tw.bin  = (const float*)d_in[17];
  tw.wout = (const float*)d_in[18]; tw.bout = (const float*)d_in[19];
  tw.nw0 = (const float*)d_in[20]; tw.nb0 = (const float*)d_in[21];
  tw.nw1 = (const float*)d_in[22]; tw.nb1 = (const float*)d_in[23];
  tw.nw2 = (const float*)d_in[24]; tw.nb2 = (const float*)d_in[25];
  tw.nw3 = (const float*)d_in[26]; tw.nb3 = (const float*)d_in[27];
  tw.nw4 = (const float*)d_in[28]; tw.nb4 = (const float*)d_in[29];
  tw.nw5 = (const float*)d_in[30]; tw.nb5 = (const float*)d_in[31];
  tw.nw6 = (const float*)d_in[32]; tw.nb6 = (const float*)d_in[33];
  tw.gw0 = (const float*)d_in[34]; tw.gb0 = (const float*)d_in[35];
  tw.gw1 = (const float*)d_in[36]; tw.gb1 = (const float*)d_in[37];
  k_final<<<NV, HID, 0, stream>>>(outsv, tw, (float*)d_out);
}